// Round 1
// baseline (358.863 us; speedup 1.0000x reference)
//
#include <hip/hip_runtime.h>
#include <math.h>

// Problem constants
#define B_   32
#define P_   8
#define K_   17
#define H_   192
#define W_   192
#define HW_  (H_*W_)              // 36864
#define PB4   156672              // K*H*W/4 float4 per batch row
#define NBLKS 2048                // 8 blocks/CU persistent
#define PER_B_BLKS 64             // blocks per batch row
#define CHUNK 16384               // 64 blocks * 256 threads (float4 stride)
#define FULL_IT 9                 // 9*16384 = 147456 of 156672
#define REM4  9216                // remainder float4 per b
#define BCE4  294912              // B*H*W/4

#define KPU  (K_*P_)              // 136 stamp units per batch row
#define RADIUS 18                 // exp(-18) ~ 1.5e-8: negligible tail

// ws layout (floats)
#define WS_BLK   0                // 2048*8: (S2,Zu,Zv,A,bce) per block; slots 5-7 free
#define WS_STAMP 16384            // 4352: cross partial per (b,k,p)
#define WS_TSQ   20736            // 544: sum(t^2) per (b,k)
#define WS_CNT   7                // block-arrival counter (unused slot of blk 0)

typedef __attribute__((ext_vector_type(4))) float f4v;

__device__ inline float wave_red_sum(float v) {
    for (int o = 32; o; o >>= 1) v += __shfl_xor(v, o, 64);
    return v;
}

__device__ inline void kl_elem(float sv, float tv,
        float& S2, float& Zu, float& Zv, float& A) {
    S2 += sv*sv;
    float u = tv*0.5f, v = sv*0.5f;
    float eu = __expf(u);
    Zu += eu;
    A  += eu*(u - v);
    Zv += __expf(v);
}

// =====================================================================
// r8: single persistent kernel, 2048 x 256. Changes vs r7:
//  (a) stamps are wave-level & syncless (lane=column, 8-deep row-load
//      pipeline) -> removes 2-3 sync'd serialized stamps per block
//  (b) tsq blocks b-local ((blk&63)<17) -> tail phases share one slot
//  (c) finalize merged via threadfence + agent-scope atomic; last
//      arriving block reduces -> kills the 1-block second dispatch
//  (d) nt loads dropped (time-neutral per r6/r7; lets L3 allocate, and
//      FETCH_SIZE next round tells us if the 3.3 TB/s wall is
//      requester-side or service-side)
// MSE = S2 - 2*cross + tsq; KL max-free (r5/r6-verified).
// =====================================================================
__global__ void __launch_bounds__(256, 8) main_kernel(
        const float* __restrict__ s_pose, const float* __restrict__ t_pose,
        const float* __restrict__ kps,    const int* __restrict__ vis,
        const float* __restrict__ s_seg,  const float* __restrict__ mask,
        float* __restrict__ ws, float* __restrict__ out) {
    __shared__ float sred[4][5];
    // finalize scratch (cold path; ~7.4 KB, occupancy unaffected)
    __shared__ float rS2[B_][8], rZu[B_][8], rZv[B_][8], rA[B_][8];
    __shared__ float rCr[B_][8], rTq[B_][8];
    __shared__ int   rVs[B_][8];
    __shared__ float skl[B_], skp[B_];
    __shared__ float bw4[4];
    __shared__ int   is_last;

    const int blk = blockIdx.x;
    const int tid = threadIdx.x;
    const float inv18 = 1.0f / 18.0f;

    // ---------------- phase 1: pose stream (b-pinned) ----------------
    const int b  = blk >> 6;                     // 64 blocks per b
    const int lg = ((blk & 63) << 8) | tid;      // 0..16383 within b
    const f4v* s4 = (const f4v*)s_pose + (size_t)b*PB4 + lg;
    const f4v* t4 = (const f4v*)t_pose + (size_t)b*PB4 + lg;

    float S2 = 0.f, Zu = 0.f, Zv = 0.f, A = 0.f;
#pragma unroll 3
    for (int j = 0; j < FULL_IT; j++) {
        f4v sv = s4[(size_t)j*CHUNK];
        f4v tv = t4[(size_t)j*CHUNK];
        kl_elem(sv.x, tv.x, S2, Zu, Zv, A);
        kl_elem(sv.y, tv.y, S2, Zu, Zv, A);
        kl_elem(sv.z, tv.z, S2, Zu, Zv, A);
        kl_elem(sv.w, tv.w, S2, Zu, Zv, A);
    }
    if (lg < REM4) {
        f4v sv = s4[(size_t)FULL_IT*CHUNK];
        f4v tv = t4[(size_t)FULL_IT*CHUNK];
        kl_elem(sv.x, tv.x, S2, Zu, Zv, A);
        kl_elem(sv.y, tv.y, S2, Zu, Zv, A);
        kl_elem(sv.z, tv.z, S2, Zu, Zv, A);
        kl_elem(sv.w, tv.w, S2, Zu, Zv, A);
    }

    // ---------------- phase 2: BCE (one iter per thread) ----------------
    float bce = 0.f;
    {
        int gid = (blk << 8) | tid;
        if (gid < BCE4) {
            f4v xv = ((const f4v*)s_seg)[gid];
            f4v mv = ((const f4v*)mask)[gid];
            bce += fmaxf(xv.x, 0.f) - xv.x*mv.x + log1pf(__expf(-fabsf(xv.x)));
            bce += fmaxf(xv.y, 0.f) - xv.y*mv.y + log1pf(__expf(-fabsf(xv.y)));
            bce += fmaxf(xv.z, 0.f) - xv.z*mv.z + log1pf(__expf(-fabsf(xv.z)));
            bce += fmaxf(xv.w, 0.f) - xv.w*mv.w + log1pf(__expf(-fabsf(xv.w)));
        }
    }

    // ---------------- single 5-value block reduction ----------------
    S2  = wave_red_sum(S2);
    Zu  = wave_red_sum(Zu);
    Zv  = wave_red_sum(Zv);
    A   = wave_red_sum(A);
    bce = wave_red_sum(bce);
    {
        int w = tid >> 6;
        if ((tid & 63) == 0) {
            sred[w][0] = S2; sred[w][1] = Zu; sred[w][2] = Zv;
            sred[w][3] = A;  sred[w][4] = bce;
        }
    }
    __syncthreads();
    if (tid == 0) {
        float* o = ws + WS_BLK + (size_t)blk * 8;
#pragma unroll
        for (int c = 0; c < 5; c++)
            o[c] = sred[0][c] + sred[1][c] + sred[2][c] + sred[3][c];
    }

    // -------- phase 3: cross-term stamps, wave-level, syncless ----------
    // wave lw (0..255) within this b-group handles stamp j=lw if j<136.
    // lane = column within the window; rows pipelined 8 deep.
    {
        const int wv = tid >> 6, lane = tid & 63;
        const int lw = ((blk & 63) << 2) | wv;
        if (lw < KPU) {
            int kk = lw >> 3, pp = lw & 7;
            int ki = (b*P_ + pp)*K_ + kk;
            float kx = kps[ki*2 + 0];
            float ky = kps[ki*2 + 1];
            int   vv = vis[ki];
            float fx = floorf(kx * 191.f);   // row center
            float fy = floorf(ky * 191.f);   // col center
            bool ok = (vv > 0) && fx >= 0.f && fx < 192.f && fy >= 0.f && fy < 192.f;
            float acc = 0.f;
            if (ok) {
                int X0 = max(0, (int)fx - RADIUS), X1 = min(H_-1, (int)fx + RADIUS);
                int Y0 = max(0, (int)fy - RADIUS), Y1 = min(W_-1, (int)fy + RADIUS);
                int nr = X1 - X0 + 1, nc = Y1 - Y0 + 1;   // each in [19,37]
                float gy_l = 0.f;
                if (lane < nc) {
                    float d = (float)(Y0 + lane) - fy;
                    gy_l = __expf(-d*d*inv18);
                }
                const float* pb = s_pose + (size_t)(b*K_ + kk)*HW_ + Y0 + lane;
                float racc = 0.f;
                for (int r0 = 0; r0 < nr; r0 += 8) {
                    float vbuf[8];
#pragma unroll
                    for (int u = 0; u < 8; u++) {
                        int r = r0 + u;
                        vbuf[u] = (r < nr && lane < nc) ? pb[(size_t)(X0 + r)*W_] : 0.f;
                    }
#pragma unroll
                    for (int u = 0; u < 8; u++) {
                        float d = (float)(X0 + r0 + u) - fx;
                        racc += vbuf[u] * __expf(-d*d*inv18);
                    }
                }
                acc = racc * gy_l;
            }
            acc = wave_red_sum(acc);
            if (lane == 0) ws[WS_STAMP + b*KPU + lw] = acc;
        }
    }

    // -------- phase 4: tsq closed form, b-local ((blk&63)<17) ----------
    {
        int kk4 = blk & 63;
        if (kk4 < K_) {
            __syncthreads();   // sred reuse
            int pq = tid >> 2, p = pq >> 3, q = pq & 7, ln = tid & 3;
            float kxp = kps[((b*P_ + p)*K_ + kk4)*2 + 0];
            float kyp = kps[((b*P_ + p)*K_ + kk4)*2 + 1];
            float kxq = kps[((b*P_ + q)*K_ + kk4)*2 + 0];
            float kyq = kps[((b*P_ + q)*K_ + kk4)*2 + 1];
            int vp = vis[(b*P_ + p)*K_ + kk4];
            int vq = vis[(b*P_ + q)*K_ + kk4];
            float axp = floorf(kxp * 191.f), ayp = floorf(kyp * 191.f);
            float axq = floorf(kxq * 191.f), ayq = floorf(kyq * 191.f);
            bool okp = (vp > 0) && axp >= 0.f && axp < 192.f && ayp >= 0.f && ayp < 192.f;
            bool okq = (vq > 0) && axq >= 0.f && axq < 192.f && ayq >= 0.f && ayq < 192.f;
            float sx = 0.f, sy = 0.f;
            int i0 = ln * 48;
            for (int i = i0; i < i0 + 48; i++) {
                float da = (float)i - axp, db = (float)i - axq;
                sx += __expf(-(da*da + db*db)*inv18);
                float ea = (float)i - ayp, eb = (float)i - ayq;
                sy += __expf(-(ea*ea + eb*eb)*inv18);
            }
            sx += __shfl_xor(sx, 1, 64); sy += __shfl_xor(sy, 1, 64);
            sx += __shfl_xor(sx, 2, 64); sy += __shfl_xor(sy, 2, 64);
            float val = (ln == 0 && okp && okq) ? sx * sy : 0.f;
            val = wave_red_sum(val);
            if ((tid & 63) == 0) sred[tid >> 6][0] = val;
            __syncthreads();
            if (tid == 0)
                ws[WS_TSQ + b*K_ + kk4] = sred[0][0] + sred[1][0] + sred[2][0] + sred[3][0];
        }
    }

    // -------- arrival: last block finalizes (no waiting => no deadlock) --
    __syncthreads();
    if (tid == 0) {
        __threadfence();   // agent-scope release of all this block's ws writes
        unsigned prev = __hip_atomic_fetch_add((unsigned*)(ws + WS_CNT), 1u,
                            __ATOMIC_ACQ_REL, __HIP_MEMORY_SCOPE_AGENT);
        is_last = (prev == NBLKS - 1);
    }
    __syncthreads();
    if (!is_last) return;

    // ======================= finalize (last block) =======================
    {
        int b2 = tid >> 3, s = tid & 7;
        float fS2 = 0.f, fZu = 0.f, fZv = 0.f, fA = 0.f, cr = 0.f, tq = 0.f;
        for (int j = s; j < PER_B_BLKS; j += 8) {
            const float* p = ws + WS_BLK + (size_t)(b2*PER_B_BLKS + j) * 8;
            fS2 += p[0]; fZu += p[1]; fZv += p[2]; fA += p[3];
        }
        for (int j = s; j < KPU; j += 8) cr += ws[WS_STAMP + b2*KPU + j];
        for (int j = s; j < K_;  j += 8) tq += ws[WS_TSQ + b2*K_ + j];
        int vsum = 0;
        for (int m = s; m < P_*K_; m += 8) vsum += vis[b2*(P_*K_) + m];
        rS2[b2][s] = fS2; rZu[b2][s] = fZu; rZv[b2][s] = fZv; rA[b2][s] = fA;
        rCr[b2][s] = cr;  rTq[b2][s] = tq;  rVs[b2][s] = vsum;

        float bce2 = 0.f;
        for (int i = tid; i < NBLKS; i += 256)
            bce2 += ws[WS_BLK + (size_t)i * 8 + 4];
        bce2 = wave_red_sum(bce2);
        if ((tid & 63) == 0) bw4[tid >> 6] = bce2;
        __syncthreads();

        if (tid < B_) {
            float tS2=0.f, tZu=0.f, tZv=0.f, tA=0.f, tCr=0.f, tTq=0.f; int tVs=0;
#pragma unroll
            for (int q2 = 0; q2 < 8; q2++) {
                tS2 += rS2[tid][q2]; tZu += rZu[tid][q2]; tZv += rZv[tid][q2];
                tA  += rA[tid][q2];  tCr += rCr[tid][q2]; tTq += rTq[tid][q2];
                tVs += rVs[tid][q2];
            }
            float mse = tS2 - 2.f*tCr + tTq;
            skl[tid] = tA/tZu + (logf(tZv) - logf(tZu));
            skp[tid] = mse / ((float)tVs + 1e-6f);
        }
        __syncthreads();

        if (tid == 0) {
            float kl = 0.f, kpv = 0.f;
            for (int i = 0; i < B_; i++) { kl += skl[i]; kpv += skp[i]; }
            float bsum = bw4[0] + bw4[1] + bw4[2] + bw4[3];
            float pose_distill = 4.0f * kl / (float)B_;   // TEMP^2=4, batchmean
            float task_seg  = bsum / (float)(B_ * HW_);
            float task_pose = kpv / (float)B_;
            // seg_distill == 0 exactly (softmax over a size-1 channel axis)
            out[0] = 0.5f * pose_distill + 0.5f * (task_seg + task_pose);
        }
    }
}

extern "C" void kernel_launch(void* const* d_in, const int* in_sizes, int n_in,
                              void* d_out, int out_size, void* d_ws, size_t ws_size,
                              hipStream_t stream) {
    const float* s_seg  = (const float*)d_in[0];
    const float* s_pose = (const float*)d_in[1];
    // d_in[2] (t_seg_logits) unused: seg_distill == 0 exactly
    const float* t_pose = (const float*)d_in[3];
    const float* mask   = (const float*)d_in[4];
    const float* kps    = (const float*)d_in[5];
    const int*   vis    = (const int*)d_in[6];
    float* out = (float*)d_out;
    float* ws  = (float*)d_ws;

    // zero the arrival counter (ws[7]); graph-capture-safe stream memset
    hipMemsetAsync((char*)d_ws + WS_CNT*sizeof(float), 0, sizeof(unsigned), stream);
    main_kernel<<<NBLKS, 256, 0, stream>>>(s_pose, t_pose, kps, vis,
                                           s_seg, mask, ws, out);
}

// Round 2
// 206.993 us; speedup vs baseline: 1.7337x; 1.7337x over previous
//
#include <hip/hip_runtime.h>
#include <math.h>

// Problem constants
#define B_   32
#define P_   8
#define K_   17
#define H_   192
#define W_   192
#define HW_  (H_*W_)              // 36864
#define PB4   156672              // K*H*W/4 float4 per batch row
#define NBLKS 2048                // 8 blocks/CU persistent
#define PER_B_BLKS 64             // blocks per batch row
#define CHUNK 16384               // 64 blocks * 256 threads (float4 stride)
#define FULL_IT 9                 // 9*16384 = 147456 of 156672
#define REM4  9216                // remainder float4 per b
#define BCE4  294912              // B*H*W/4

#define KPU  (K_*P_)              // 136 stamp units per batch row
#define TSQ_UNITS   (B_*K_)       // 544
#define RADIUS 18                 // exp(-18) ~ 1.5e-8: negligible tail

// ws layout (floats)
#define WS_BLK   0                // 2048*8: (S2,Zu,Zv,A,bce) per block
#define WS_STAMP 16384            // 4352: cross partial per (b,k,p)
#define WS_TSQ   20736            // 544: sum(t^2) per (b,k)

typedef __attribute__((ext_vector_type(4))) float f4v;

__device__ inline f4v ntload4(const float* p) {
    return __builtin_nontemporal_load((const f4v*)p);
}

__device__ inline float wave_red_sum(float v) {
    for (int o = 32; o; o >>= 1) v += __shfl_xor(v, o, 64);
    return v;
}

__device__ inline void kl_elem(float sv, float tv,
        float& S2, float& Zu, float& Zv, float& A) {
    S2 += sv*sv;
    float u = tv*0.5f, v = sv*0.5f;
    float eu = __expf(u);
    Zu += eu;
    A  += eu*(u - v);
    Zv += __expf(v);
}

// =====================================================================
// r9: revert r8's merged finalize (per-block agent-scope fence = L2
// writeback per block on non-coherent XCDs -> 180us serialization,
// measured 52->234us). Two-kernel structure restored exactly as the
// 206us r7 config for phases 1/2; KEEP r8's two tail improvements:
//  (a) phase 3 stamps wave-level & syncless (no per-stamp barriers)
//  (b) phase 4 tsq b-local ((blk&63)<17) so tails overlap per b-group
// MSE = S2 - 2*cross + tsq; KL max-free (r5/r6-verified, absmax 0).
// =====================================================================
__global__ void __launch_bounds__(256) main_kernel(
        const float* __restrict__ s_pose, const float* __restrict__ t_pose,
        const float* __restrict__ kps,    const int* __restrict__ vis,
        const float* __restrict__ s_seg,  const float* __restrict__ mask,
        float* __restrict__ ws) {
    __shared__ float sred[4][5];

    const int blk = blockIdx.x;
    const int tid = threadIdx.x;
    const float inv18 = 1.0f / 18.0f;

    // ---------------- phase 1: pose stream (b-pinned) ----------------
    const int b  = blk >> 6;                     // 64 blocks per b
    const int lg = ((blk & 63) << 8) | tid;      // 0..16383 within b
    const float* s4 = s_pose + ((size_t)b*PB4 + lg)*4;
    const float* t4 = t_pose + ((size_t)b*PB4 + lg)*4;

    float S2 = 0.f, Zu = 0.f, Zv = 0.f, A = 0.f;
#pragma unroll 3
    for (int j = 0; j < FULL_IT; j++) {
        f4v sv = ntload4(s4 + (size_t)j*CHUNK*4);
        f4v tv = ntload4(t4 + (size_t)j*CHUNK*4);
        kl_elem(sv.x, tv.x, S2, Zu, Zv, A);
        kl_elem(sv.y, tv.y, S2, Zu, Zv, A);
        kl_elem(sv.z, tv.z, S2, Zu, Zv, A);
        kl_elem(sv.w, tv.w, S2, Zu, Zv, A);
    }
    if (lg < REM4) {
        f4v sv = ntload4(s4 + (size_t)FULL_IT*CHUNK*4);
        f4v tv = ntload4(t4 + (size_t)FULL_IT*CHUNK*4);
        kl_elem(sv.x, tv.x, S2, Zu, Zv, A);
        kl_elem(sv.y, tv.y, S2, Zu, Zv, A);
        kl_elem(sv.z, tv.z, S2, Zu, Zv, A);
        kl_elem(sv.w, tv.w, S2, Zu, Zv, A);
    }

    // ---------------- phase 2: BCE (one iter per thread) ----------------
    float bce = 0.f;
    {
        int gid = (blk << 8) | tid;
        if (gid < BCE4) {
            f4v xv = ntload4(s_seg + (size_t)gid*4);
            f4v mv = ntload4(mask  + (size_t)gid*4);
            bce += fmaxf(xv.x, 0.f) - xv.x*mv.x + log1pf(__expf(-fabsf(xv.x)));
            bce += fmaxf(xv.y, 0.f) - xv.y*mv.y + log1pf(__expf(-fabsf(xv.y)));
            bce += fmaxf(xv.z, 0.f) - xv.z*mv.z + log1pf(__expf(-fabsf(xv.z)));
            bce += fmaxf(xv.w, 0.f) - xv.w*mv.w + log1pf(__expf(-fabsf(xv.w)));
        }
    }

    // ---------------- single 5-value block reduction ----------------
    S2  = wave_red_sum(S2);
    Zu  = wave_red_sum(Zu);
    Zv  = wave_red_sum(Zv);
    A   = wave_red_sum(A);
    bce = wave_red_sum(bce);
    {
        int w = tid >> 6;
        if ((tid & 63) == 0) {
            sred[w][0] = S2; sred[w][1] = Zu; sred[w][2] = Zv;
            sred[w][3] = A;  sred[w][4] = bce;
        }
    }
    __syncthreads();
    if (tid == 0) {
        float* o = ws + WS_BLK + (size_t)blk * 8;
#pragma unroll
        for (int c = 0; c < 5; c++)
            o[c] = sred[0][c] + sred[1][c] + sred[2][c] + sred[3][c];
    }

    // -------- phase 3: cross-term stamps, wave-level, syncless ----------
    // wave lw (0..255) within this b-group handles stamp j=lw if j<136.
    // lane = column within the window; rows pipelined 8 deep. L2-warm
    // (block streamed row b in phase 1).
    {
        const int wv = tid >> 6, lane = tid & 63;
        const int lw = ((blk & 63) << 2) | wv;
        if (lw < KPU) {
            int kk = lw >> 3, pp = lw & 7;
            int ki = (b*P_ + pp)*K_ + kk;
            float kx = kps[ki*2 + 0];
            float ky = kps[ki*2 + 1];
            int   vv = vis[ki];
            float fx = floorf(kx * 191.f);   // row center
            float fy = floorf(ky * 191.f);   // col center
            bool ok = (vv > 0) && fx >= 0.f && fx < 192.f && fy >= 0.f && fy < 192.f;
            float acc = 0.f;
            if (ok) {
                int X0 = max(0, (int)fx - RADIUS), X1 = min(H_-1, (int)fx + RADIUS);
                int Y0 = max(0, (int)fy - RADIUS), Y1 = min(W_-1, (int)fy + RADIUS);
                int nr = X1 - X0 + 1, nc = Y1 - Y0 + 1;   // each in [19,37]
                float gy_l = 0.f;
                if (lane < nc) {
                    float d = (float)(Y0 + lane) - fy;
                    gy_l = __expf(-d*d*inv18);
                }
                const float* pb = s_pose + (size_t)(b*K_ + kk)*HW_ + Y0 + lane;
                float racc = 0.f;
                for (int r0 = 0; r0 < nr; r0 += 8) {
                    float vbuf[8];
#pragma unroll
                    for (int u = 0; u < 8; u++) {
                        int r = r0 + u;
                        vbuf[u] = (r < nr && lane < nc) ? pb[(size_t)(X0 + r)*W_] : 0.f;
                    }
#pragma unroll
                    for (int u = 0; u < 8; u++) {
                        float d = (float)(X0 + r0 + u) - fx;
                        racc += vbuf[u] * __expf(-d*d*inv18);
                    }
                }
                acc = racc * gy_l;
            }
            acc = wave_red_sum(acc);
            if (lane == 0) ws[WS_STAMP + b*KPU + lw] = acc;
        }
    }

    // -------- phase 4: tsq closed form, b-local ((blk&63)<17) ----------
    {
        int kk4 = blk & 63;   // uniform per block: no divergent barrier
        if (kk4 < K_) {
            __syncthreads();   // sred reuse after phase-1 reduction
            int pq = tid >> 2, p = pq >> 3, q = pq & 7, ln = tid & 3;
            float kxp = kps[((b*P_ + p)*K_ + kk4)*2 + 0];
            float kyp = kps[((b*P_ + p)*K_ + kk4)*2 + 1];
            float kxq = kps[((b*P_ + q)*K_ + kk4)*2 + 0];
            float kyq = kps[((b*P_ + q)*K_ + kk4)*2 + 1];
            int vp = vis[(b*P_ + p)*K_ + kk4];
            int vq = vis[(b*P_ + q)*K_ + kk4];
            float axp = floorf(kxp * 191.f), ayp = floorf(kyp * 191.f);
            float axq = floorf(kxq * 191.f), ayq = floorf(kyq * 191.f);
            bool okp = (vp > 0) && axp >= 0.f && axp < 192.f && ayp >= 0.f && ayp < 192.f;
            bool okq = (vq > 0) && axq >= 0.f && axq < 192.f && ayq >= 0.f && ayq < 192.f;
            float sx = 0.f, sy = 0.f;
            int i0 = ln * 48;
            for (int i = i0; i < i0 + 48; i++) {
                float da = (float)i - axp, db = (float)i - axq;
                sx += __expf(-(da*da + db*db)*inv18);
                float ea = (float)i - ayp, eb = (float)i - ayq;
                sy += __expf(-(ea*ea + eb*eb)*inv18);
            }
            sx += __shfl_xor(sx, 1, 64); sy += __shfl_xor(sy, 1, 64);
            sx += __shfl_xor(sx, 2, 64); sy += __shfl_xor(sy, 2, 64);
            float val = (ln == 0 && okp && okq) ? sx * sy : 0.f;
            val = wave_red_sum(val);
            if ((tid & 63) == 0) sred[tid >> 6][0] = val;
            __syncthreads();
            if (tid == 0)
                ws[WS_TSQ + b*K_ + kk4] = sred[0][0] + sred[1][0] + sred[2][0] + sred[3][0];
        }
    }
}

// =====================================================================
// finalize: 1 block x 256 threads; 8 threads per batch row b.
//   mse_b = S2_b - 2*cross_b + tsq_b ;  KL_b = A/Zu + log(Zv) - log(Zu)
// =====================================================================
__global__ void __launch_bounds__(256) finalize_kernel(
        const float* __restrict__ ws, const int* __restrict__ vis,
        float* __restrict__ out) {
    __shared__ float rS2[B_][8], rZu[B_][8], rZv[B_][8], rA[B_][8];
    __shared__ float rCr[B_][8], rTq[B_][8];
    __shared__ int   rVs[B_][8];
    __shared__ float skl[B_], skp[B_];
    __shared__ float bw[4];
    int tid = threadIdx.x;
    int b = tid >> 3, s = tid & 7;

    float S2 = 0.f, Zu = 0.f, Zv = 0.f, A = 0.f, cr = 0.f, tq = 0.f;
    for (int j = s; j < PER_B_BLKS; j += 8) {
        const float* p = ws + WS_BLK + (size_t)(b*PER_B_BLKS + j) * 8;
        S2 += p[0]; Zu += p[1]; Zv += p[2]; A += p[3];
    }
    for (int j = s; j < KPU; j += 8) cr += ws[WS_STAMP + b*KPU + j];
    for (int j = s; j < K_;  j += 8) tq += ws[WS_TSQ + b*K_ + j];
    int vs = 0;
    for (int m = s; m < P_*K_; m += 8) vs += vis[b*(P_*K_) + m];
    rS2[b][s] = S2; rZu[b][s] = Zu; rZv[b][s] = Zv; rA[b][s] = A;
    rCr[b][s] = cr; rTq[b][s] = tq; rVs[b][s] = vs;

    float bce = 0.f;
    for (int i = tid; i < NBLKS; i += 256)
        bce += ws[WS_BLK + (size_t)i * 8 + 4];
    bce = wave_red_sum(bce);
    if ((tid & 63) == 0) bw[tid >> 6] = bce;
    __syncthreads();

    if (tid < B_) {
        float tS2=0.f, tZu=0.f, tZv=0.f, tA=0.f, tCr=0.f, tTq=0.f; int tVs=0;
#pragma unroll
        for (int q2 = 0; q2 < 8; q2++) {
            tS2 += rS2[tid][q2]; tZu += rZu[tid][q2]; tZv += rZv[tid][q2];
            tA  += rA[tid][q2];  tCr += rCr[tid][q2]; tTq += rTq[tid][q2];
            tVs += rVs[tid][q2];
        }
        float mse = tS2 - 2.f*tCr + tTq;
        skl[tid] = tA/tZu + (logf(tZv) - logf(tZu));
        skp[tid] = mse / ((float)tVs + 1e-6f);
    }
    __syncthreads();

    if (tid == 0) {
        float kl = 0.f, kpv = 0.f;
        for (int i = 0; i < B_; i++) { kl += skl[i]; kpv += skp[i]; }
        float bsum = bw[0] + bw[1] + bw[2] + bw[3];
        float pose_distill = 4.0f * kl / (float)B_;   // TEMP^2=4, batchmean
        float task_seg  = bsum / (float)(B_ * HW_);
        float task_pose = kpv / (float)B_;
        // seg_distill == 0 exactly (softmax over a size-1 channel axis)
        out[0] = 0.5f * pose_distill + 0.5f * (task_seg + task_pose);
    }
}

extern "C" void kernel_launch(void* const* d_in, const int* in_sizes, int n_in,
                              void* d_out, int out_size, void* d_ws, size_t ws_size,
                              hipStream_t stream) {
    const float* s_seg  = (const float*)d_in[0];
    const float* s_pose = (const float*)d_in[1];
    // d_in[2] (t_seg_logits) unused: seg_distill == 0 exactly
    const float* t_pose = (const float*)d_in[3];
    const float* mask   = (const float*)d_in[4];
    const float* kps    = (const float*)d_in[5];
    const int*   vis    = (const int*)d_in[6];
    float* out = (float*)d_out;
    float* ws  = (float*)d_ws;

    main_kernel<<<NBLKS, 256, 0, stream>>>(s_pose, t_pose, kps, vis,
                                           s_seg, mask, ws);
    finalize_kernel<<<1, 256, 0, stream>>>(ws, vis, out);
}